// Round 1
// baseline (502.536 us; speedup 1.0000x reference)
//
#include <hip/hip_runtime.h>
#include <math.h>

namespace {
constexpr int IH = 224, IW = 224;
constexpr int H2 = 67, W2 = 67;
constexpr int MH = 56, MW = 56;
constexpr int CI = 3, CM = 21;
constexpr int ND = 6;
constexpr int K = 48;
constexpr int HW = IH * IW;    // 50176
constexpr int HW2 = H2 * W2;   // 4489
constexpr float EPS = 1e-8f;
}

struct PosArr { float v[K]; };

// ---------------- bilinear downsample imgs 224->67 (align_corners) ----------
__global__ void k_img_down(const float* __restrict__ img, float* __restrict__ img2) {
    int t = blockIdx.x * blockDim.x + threadIdx.x;
    if (t >= CI * HW2) return;
    int c = t / HW2, r = t % HW2;
    int y = r / W2, x = r % W2;
    float fy = (float)y * ((float)(IH - 1) / (float)(H2 - 1));
    float fx = (float)x * ((float)(IW - 1) / (float)(W2 - 1));
    int y0 = (int)floorf(fy); int y1 = min(y0 + 1, IH - 1); float wy = fy - (float)y0;
    int x0 = (int)floorf(fx); int x1 = min(x0 + 1, IW - 1); float wx = fx - (float)x0;
    const float* p = img + c * HW;
    float v00 = p[y0 * IW + x0], v01 = p[y0 * IW + x1];
    float v10 = p[y1 * IW + x0], v11 = p[y1 * IW + x1];
    float r0 = v00 * (1.f - wy) + v10 * wy;
    float r1 = v01 * (1.f - wy) + v11 * wy;
    img2[t] = r0 * (1.f - wx) + r1 * wx;
}

// ---------------- low-res affinity aff2 [K,67,67] ---------------------------
__global__ void k_aff2(const float* __restrict__ img2, float* __restrict__ aff2) {
    int t = blockIdx.x * blockDim.x + threadIdx.x;
    if (t >= HW2) return;
    int y = t / W2, x = t % W2;

    float av[K];
    #pragma unroll
    for (int k = 0; k < K; ++k) av[k] = 0.f;

    for (int c = 0; c < CI; ++c) {
        const float* p = img2 + c * HW2;
        float center = p[y * W2 + x];
        float nv[K];
        float sum = 0.f;
        const int DILS[ND] = {1, 2, 4, 8, 12, 24};
        #pragma unroll
        for (int di = 0; di < ND; ++di) {
            int d = DILS[di];
            int ym = max(y - d, 0), yp = min(y + d, H2 - 1);
            int xm = max(x - d, 0), xp = min(x + d, W2 - 1);
            int rows[3] = {ym, y, yp};
            int cols[3] = {xm, x, xp};
            const int KI[8] = {0, 0, 0, 1, 1, 2, 2, 2};
            const int KJ[8] = {0, 1, 2, 0, 2, 0, 1, 2};
            #pragma unroll
            for (int o = 0; o < 8; ++o) {
                float v = p[rows[KI[o]] * W2 + cols[KJ[o]]];
                nv[di * 8 + o] = v;
                sum += v;
            }
        }
        float mean = sum * (1.f / (float)K);
        float ss = 0.f;
        #pragma unroll
        for (int k = 0; k < K; ++k) { float dd = nv[k] - mean; ss += dd * dd; }
        float stdv = sqrtf(ss * (1.f / (float)(K - 1)));
        float inv = 1.f / (stdv + EPS);
        #pragma unroll
        for (int k = 0; k < K; ++k) { float tt = fabsf(nv[k] - center) * inv; av[k] += tt * tt; }
    }
    #pragma unroll
    for (int k = 0; k < K; ++k)
        aff2[k * HW2 + t] = -av[k] * (1.f / (float)CI);
}

// ---------------- full-res aff + upsampled aff2 + pos -> aff_total ----------
__global__ void k_aff_total(const float* __restrict__ img,
                            const float* __restrict__ aff2,
                            float* __restrict__ afft, PosArr pos) {
    int t = blockIdx.x * blockDim.x + threadIdx.x;
    if (t >= HW) return;
    int y = t / IW, x = t % IW;

    float av[K];
    #pragma unroll
    for (int k = 0; k < K; ++k) av[k] = 0.f;

    for (int c = 0; c < CI; ++c) {
        const float* p = img + c * HW;
        float center = p[y * IW + x];
        float nv[K];
        float sum = 0.f;
        const int DILS[ND] = {1, 2, 4, 8, 12, 24};
        #pragma unroll
        for (int di = 0; di < ND; ++di) {
            int d = DILS[di];
            int ym = max(y - d, 0), yp = min(y + d, IH - 1);
            int xm = max(x - d, 0), xp = min(x + d, IW - 1);
            int rows[3] = {ym, y, yp};
            int cols[3] = {xm, x, xp};
            const int KI[8] = {0, 0, 0, 1, 1, 2, 2, 2};
            const int KJ[8] = {0, 1, 2, 0, 2, 0, 1, 2};
            #pragma unroll
            for (int o = 0; o < 8; ++o) {
                float v = p[rows[KI[o]] * IW + cols[KJ[o]]];
                nv[di * 8 + o] = v;
                sum += v;
            }
        }
        float mean = sum * (1.f / (float)K);
        float ss = 0.f;
        #pragma unroll
        for (int k = 0; k < K; ++k) { float dd = nv[k] - mean; ss += dd * dd; }
        float stdv = sqrtf(ss * (1.f / (float)(K - 1)));
        float inv = 1.f / (stdv + EPS);
        #pragma unroll
        for (int k = 0; k < K; ++k) { float tt = fabsf(nv[k] - center) * inv; av[k] += tt * tt; }
    }

    // aff = -(mean over c) / W1^2 ; then softmax over k
    const float sc = -(1.f / (float)CI) / (0.3f * 0.3f);
    float m1 = -INFINITY;
    #pragma unroll
    for (int k = 0; k < K; ++k) { av[k] *= sc; m1 = fmaxf(m1, av[k]); }
    float e1 = 0.f;
    #pragma unroll
    for (int k = 0; k < K; ++k) { av[k] = expf(av[k] - m1); e1 += av[k]; }
    float r1 = 1.f / e1;

    // bilinear sample of aff2 (67x67 -> 224x224, align_corners), then softmax
    float fy = (float)y * ((float)(H2 - 1) / (float)(IH - 1));
    float fx = (float)x * ((float)(W2 - 1) / (float)(IW - 1));
    int y0 = (int)floorf(fy); int y1 = min(y0 + 1, H2 - 1); float wy = fy - (float)y0;
    int x0 = (int)floorf(fx); int x1 = min(x0 + 1, W2 - 1); float wx = fx - (float)x0;
    int i00 = y0 * W2 + x0, i01 = y0 * W2 + x1, i10 = y1 * W2 + x0, i11 = y1 * W2 + x1;
    float w00 = (1.f - wy) * (1.f - wx), w01 = (1.f - wy) * wx;
    float w10 = wy * (1.f - wx), w11 = wy * wx;

    float a2[K];
    float m2 = -INFINITY;
    #pragma unroll
    for (int k = 0; k < K; ++k) {
        const float* q = aff2 + k * HW2;
        float v = q[i00] * w00 + q[i01] * w01 + q[i10] * w10 + q[i11] * w11;
        a2[k] = v;
        m2 = fmaxf(m2, v);
    }
    float e2 = 0.f;
    #pragma unroll
    for (int k = 0; k < K; ++k) { a2[k] = expf(a2[k] - m2); e2 += a2[k]; }
    float r2 = 1.f / e2;

    #pragma unroll
    for (int k = 0; k < K; ++k)
        afft[k * HW + t] = av[k] * r1 + a2[k] * r2 + pos.v[k];
}

// ---------------- mask upsample 56 -> 224 -----------------------------------
__global__ void k_mask_up(const float* __restrict__ m, float* __restrict__ mu) {
    int t = blockIdx.x * blockDim.x + threadIdx.x;
    if (t >= CM * HW) return;
    int c = t / HW, r = t % HW;
    int y = r / IW, x = r % IW;
    float fy = (float)y * ((float)(MH - 1) / (float)(IH - 1));
    float fx = (float)x * ((float)(MW - 1) / (float)(IW - 1));
    int y0 = (int)floorf(fy); int y1 = min(y0 + 1, MH - 1); float wy = fy - (float)y0;
    int x0 = (int)floorf(fx); int x1 = min(x0 + 1, MW - 1); float wx = fx - (float)x0;
    const float* p = m + c * MH * MW;
    float v00 = p[y0 * MW + x0], v01 = p[y0 * MW + x1];
    float v10 = p[y1 * MW + x0], v11 = p[y1 * MW + x1];
    float r0 = v00 * (1.f - wy) + v10 * wy;
    float r1 = v01 * (1.f - wy) + v11 * wy;
    mu[t] = r0 * (1.f - wx) + r1 * wx;
}

// ---------------- one propagation iteration ---------------------------------
__global__ void k_prop(const float* __restrict__ min_,
                       const float* __restrict__ afft,
                       float* __restrict__ mout) {
    int t = blockIdx.x * blockDim.x + threadIdx.x;
    if (t >= CM * HW) return;
    int c = t / HW, r = t % HW;
    int y = r / IW, x = r % IW;
    const float* p = min_ + c * HW;
    const float* a = afft + r;

    float acc = 0.f;
    const int DILS[ND] = {1, 2, 4, 8, 12, 24};
    #pragma unroll
    for (int di = 0; di < ND; ++di) {
        int d = DILS[di];
        int ym = max(y - d, 0) * IW, yc = y * IW, yp = min(y + d, IH - 1) * IW;
        int xm = max(x - d, 0), xp = min(x + d, IW - 1);
        int kb = di * 8;
        acc += p[ym + xm] * a[(kb + 0) * HW];
        acc += p[ym + x ] * a[(kb + 1) * HW];
        acc += p[ym + xp] * a[(kb + 2) * HW];
        acc += p[yc + xm] * a[(kb + 3) * HW];
        acc += p[yc + xp] * a[(kb + 4) * HW];
        acc += p[yp + xm] * a[(kb + 5) * HW];
        acc += p[yp + x ] * a[(kb + 6) * HW];
        acc += p[yp + xp] * a[(kb + 7) * HW];
    }
    mout[t] = acc;
}

extern "C" void kernel_launch(void* const* d_in, const int* in_sizes, int n_in,
                              void* d_out, int out_size, void* d_ws, size_t ws_size,
                              hipStream_t stream) {
    const float* imgs  = (const float*)d_in[0];
    const float* masks = (const float*)d_in[1];
    float* out = (float*)d_out;

    float* ws = (float*)d_ws;
    float* imgs2 = ws;                       // CI*HW2 = 13467 -> pad to 16384
    float* aff2  = imgs2 + 16384;            // K*HW2  = 215472
    float* afft  = aff2 + K * HW2;           // K*HW   = 2408448
    float* mA    = afft + K * HW;            // CM*HW  = 1053696
    float* mB    = mA + CM * HW;             // CM*HW  = 1053696

    // host-side positional softmax (input-independent, same every call)
    PosArr pos;
    {
        double pv[K];
        const int dil[ND] = {1, 2, 4, 8, 12, 24};
        const double s2 = sqrt(2.0);
        for (int di = 0; di < ND; ++di)
            for (int o = 0; o < 8; ++o) {
                double base = (o == 0 || o == 2 || o == 5 || o == 7) ? s2 : 1.0;
                pv[di * 8 + o] = base * (double)dil[di];
            }
        double sum = 0.0; for (int k = 0; k < K; ++k) sum += pv[k];
        double mean = sum / K;
        double ssd = 0.0; for (int k = 0; k < K; ++k) { double d0 = pv[k] - mean; ssd += d0 * d0; }
        double stdv = sqrt(ssd / (K - 1));
        double pa[K];
        double mx = -1e300;
        for (int k = 0; k < K; ++k) {
            double u = pv[k] / (stdv + 1e-8) / 0.3;
            pa[k] = -u * u;
            if (pa[k] > mx) mx = pa[k];
        }
        double es = 0.0, ev[K];
        for (int k = 0; k < K; ++k) { ev[k] = exp(pa[k] - mx); es += ev[k]; }
        for (int k = 0; k < K; ++k) pos.v[k] = (float)(ev[k] / es);
    }

    dim3 blk(256);
    k_img_down<<<(CI * HW2 + 255) / 256, blk, 0, stream>>>(imgs, imgs2);
    k_aff2<<<(HW2 + 255) / 256, blk, 0, stream>>>(imgs2, aff2);
    k_aff_total<<<(HW + 255) / 256, blk, 0, stream>>>(imgs, aff2, afft, pos);
    k_mask_up<<<(CM * HW + 255) / 256, blk, 0, stream>>>(masks, mA);

    float* bufs[2] = {mA, mB};
    const float* cur = mA;
    for (int i = 0; i < 10; ++i) {
        float* o = (i == 9) ? out : bufs[(i + 1) & 1];
        k_prop<<<(CM * HW + 255) / 256, blk, 0, stream>>>(cur, afft, o);
        cur = o;
    }
}